// Round 8
// baseline (278.951 us; speedup 1.0000x reference)
//
#include <hip/hip_runtime.h>
#include <stdint.h>

#define S_LEN  8192
#define G_LEN  128
#define E_DIM  1024
#define H_NUM  16
#define BS_LEN 512
#define R_TOT  8320          // G + S total rows
#define KBLK   128           // 1024/8 k-blocks
#define XBLK   1040          // R_TOT/8
#define NSPL   10            // global-attn key splits
#define SPLW   832           // keys per split (26 chunks of 32)

typedef _Float16 half8    __attribute__((ext_vector_type(8)));
typedef _Float16 half4    __attribute__((ext_vector_type(4)));
typedef float    floatx4  __attribute__((ext_vector_type(4)));
typedef float    floatx16 __attribute__((ext_vector_type(16)));

// Q scale = D^-0.5 * log2(e): exp(x) computed as exp2(x*log2e) with log2e folded into Q
#define QSCALE 0.18033688011112042f

// ---- workspace layout (bytes) ----
#define OFF_XP   0
#define OFF_AOP  0            // reuse: Xp dead after QKV GEMMs
#define OFF_WP   17039360
#define SZ_WP1   2097152
#define OFF_QP   25427968
#define OFF_KP   42467328
#define OFF_VP   59506688
#define OFF_FH   76546048     // f16 exp(mask) per key row, R_TOT entries
#define OFF_OG   76579328
#define OFF_LG   81822208

__device__ __forceinline__ floatx16 zero16() {
  floatx16 v;
#pragma unroll
  for (int i = 0; i < 16; ++i) v[i] = 0.0f;
  return v;
}
__device__ __forceinline__ floatx4 zero4() {
  floatx4 v;
#pragma unroll
  for (int i = 0; i < 4; ++i) v[i] = 0.0f;
  return v;
}

__device__ __forceinline__ void gl_lds16(const void* g, void* l) {
  __builtin_amdgcn_global_load_lds(
      (const __attribute__((address_space(1))) void*)g,
      (__attribute__((address_space(3))) void*)l, 16, 0, 0);
}

__device__ __forceinline__ int pk_f16x2(float a, float b) {
  return __builtin_bit_cast(int, __builtin_amdgcn_cvt_pkrtz(a, b));
}

// ---------------- stage 0: fused prep — pack X (LDS transpose) + pack W + fh ----------------
__global__ __launch_bounds__(256) void prep_k(const float* __restrict__ tok,
                                              const float* __restrict__ glob,
                                              const float* __restrict__ Wq,
                                              const float* __restrict__ Wk,
                                              const float* __restrict__ Wv,
                                              const float* __restrict__ Wo,
                                              const float* __restrict__ mask,
                                              char* __restrict__ ws) {
  __shared__ __align__(16) _Float16 tile[64 * 132];
  const int bx  = blockIdx.x;
  const int tid = threadIdx.x;
  if (bx < 1040) {
    const int r0 = (bx >> 3) * 64;
    const int c0 = (bx & 7) * 128;
#pragma unroll
    for (int kk = 0; kk < 8; ++kk) {
      int f   = tid + kk * 256;
      int row = f >> 5;
      int c4  = (f & 31) * 4;
      int r   = r0 + row;
      const float* src = (r < G_LEN) ? glob + (size_t)r * E_DIM
                                     : tok + (size_t)(r - G_LEN) * E_DIM;
      float4 v = *(const float4*)&src[c0 + c4];
      half4 h;
      h[0] = (_Float16)v.x; h[1] = (_Float16)v.y; h[2] = (_Float16)v.z; h[3] = (_Float16)v.w;
      *(half4*)&tile[row * 132 + c4] = h;
    }
    __syncthreads();
    _Float16* Xp = (_Float16*)(ws + OFF_XP);
#pragma unroll
    for (int uu = 0; uu < 4; ++uu) {
      int u    = tid + uu * 256;
      int kb_l = u >> 6;
      int row  = u & 63;
      half4 a = *(const half4*)&tile[row * 132 + kb_l * 8];
      half4 b = *(const half4*)&tile[row * 132 + kb_l * 8 + 4];
      half8 o;
      o[0] = a[0]; o[1] = a[1]; o[2] = a[2]; o[3] = a[3];
      o[4] = b[0]; o[5] = b[1]; o[6] = b[2]; o[7] = b[3];
      int kb = (c0 >> 3) + kb_l;
      *(half8*)&Xp[((size_t)kb * R_TOT + r0 + row) * 8] = o;
    }
  } else {
    int t = (bx - 1040) * 256 + tid;
    const int NW = 4 * KBLK * 1024;
    if (t < NW) {
      int w   = t >> 17;
      int rem = t & 131071;
      int kb  = rem >> 10;
      int n   = rem & 1023;
      const float* W = (w == 0) ? Wq : (w == 1) ? Wk : (w == 2) ? Wv : Wo;
      half8 v;
#pragma unroll
      for (int j = 0; j < 8; ++j)
        v[j] = (_Float16)W[(size_t)(kb * 8 + j) * 1024 + n];
      *(half8*)(ws + OFF_WP + (size_t)w * SZ_WP1 + (size_t)(kb * 1024 + n) * 16) = v;
    } else {
      int t2 = t - NW;
      if (t2 < R_TOT) {
        _Float16* fh = (_Float16*)(ws + OFF_FH);
        float m = (t2 < G_LEN) ? 0.0f : mask[t2 - G_LEN];
        fh[t2] = (_Float16)__expf(m);
      }
    }
  }
}

// ---------------- shared GEMM mainloop (R6 dual-LDS, swapped mfma, 84 VGPR) ----------------
// acc rows = 4 consecutive n (quad*4+r), lane l16 = m.
__device__ __forceinline__ void gemm_tile(const _Float16* __restrict__ Ap,
                                          const _Float16* __restrict__ Bp,
                                          int m0, int n0, _Float16* lds,
                                          floatx4 acc[4][4]) {
  const int tid  = threadIdx.x;
  const int wave = tid >> 6;
  const int lane = tid & 63;
  const int quad = lane >> 4;
  const int l16  = lane & 15;
  _Float16* As = lds;
  _Float16* Bs = lds + 8 * 128 * 8;
  const int wm = (wave >> 1) * 64;
  const int wn = (wave & 1) * 64;
  for (int step = 0; step < 16; ++step) {
#pragma unroll
    for (int ui = 0; ui < 8; ++ui) {
      const int u   = wave * 8 + ui;   // 32 units: 16 A, 16 B
      const int isB = u >> 4;
      const int vv  = u & 15;
      const int kb  = vv >> 1;
      const int rh  = vv & 1;
      const _Float16* src =
          isB ? Bp + (size_t)((step * 8 + kb) * 1024 + n0 + rh * 64 + lane) * 8
              : Ap + (size_t)((step * 8 + kb) * R_TOT + m0 + rh * 64 + lane) * 8;
      _Float16* dst = (isB ? Bs : As) + (kb * 128 + rh * 64) * 8;
      gl_lds16(src, dst);
    }
    __syncthreads();
#pragma unroll
    for (int kk = 0; kk < 2; ++kk) {
      half8 af[4], bf[4];
#pragma unroll
      for (int mt = 0; mt < 4; ++mt)
        af[mt] = *(const half8*)(As + ((kk * 4 + quad) * 128 + wm + mt * 16 + l16) * 8);
#pragma unroll
      for (int nt = 0; nt < 4; ++nt)
        bf[nt] = *(const half8*)(Bs + ((kk * 4 + quad) * 128 + wn + nt * 16 + l16) * 8);
#pragma unroll
      for (int mt = 0; mt < 4; ++mt)
#pragma unroll
        for (int nt = 0; nt < 4; ++nt)
          acc[mt][nt] = __builtin_amdgcn_mfma_f32_16x16x32_f16(bf[nt], af[mt], acc[mt][nt], 0, 0, 0);
    }
    __syncthreads();
  }
}

// ---------------- stage 1: Q/K/V projections (one launch per z for profiler visibility) ----------------
__global__ __launch_bounds__(256) void qkv_gemm_k(char* __restrict__ ws, int z) {
  __shared__ __align__(16) _Float16 lds[2 * 8 * 128 * 8];   // 32 KB
  const int n0 = blockIdx.x * 128;
  const int m0 = blockIdx.y * 128;
  floatx4 acc[4][4];
#pragma unroll
  for (int a = 0; a < 4; ++a)
#pragma unroll
    for (int b = 0; b < 4; ++b) acc[a][b] = zero4();
  gemm_tile((const _Float16*)(ws + OFF_XP),
            (const _Float16*)(ws + OFF_WP + (size_t)z * SZ_WP1), m0, n0, lds, acc);

  const int lane = threadIdx.x & 63, wave = threadIdx.x >> 6;
  const int quad = lane >> 4, l16 = lane & 15;
  const int wm = (wave >> 1) * 64, wn = (wave & 1) * 64;
  if (z < 2) {
    _Float16* dst = (_Float16*)(ws + (z == 0 ? OFF_QP : OFF_KP));
    const float scale = (z == 0) ? QSCALE : 1.0f;
#pragma unroll
    for (int mt = 0; mt < 4; ++mt)
#pragma unroll
      for (int nt = 0; nt < 4; ++nt) {
        int m  = m0 + wm + mt * 16 + l16;
        int nb = n0 + wn + nt * 16 + quad * 4;
        half4 h;
#pragma unroll
        for (int r = 0; r < 4; ++r) h[r] = (_Float16)(acc[mt][nt][r] * scale);
        int db = (nb >> 6) * 8 + ((nb & 63) >> 3);
        *(half4*)&dst[((size_t)db * R_TOT + m) * 8 + (nb & 7)] = h;
      }
  } else {
    _Float16* dst = (_Float16*)(ws + OFF_VP);
    const _Float16* fh = (const _Float16*)(ws + OFF_FH);
#pragma unroll
    for (int mt = 0; mt < 4; ++mt) {
      int m = m0 + wm + mt * 16 + l16;
      float fhm = (float)fh[m];
#pragma unroll
      for (int nt = 0; nt < 4; ++nt) {
        int nl = n0 + wn + nt * 16 + quad * 4;
#pragma unroll
        for (int r = 0; r < 4; ++r) {
          int n = nl + r;
          dst[(((size_t)(n >> 6) * XBLK + (m >> 3)) * 64 + (n & 63)) * 8 + (m & 7)] =
              (_Float16)(acc[mt][nt][r] * fhm);
        }
      }
    }
  }
}

// ---------------- fused attention core: 2-stage pipelined chunk loop ----------------
// kb(ci) = ci*32 + (ci >= seam ? off : 0). s carried across iterations: chunk i+1's
// QK-MFMA issues before chunk i's exp chain (MFMA pipe || VALU pipe).
__device__ __forceinline__ void attn_core(const _Float16* __restrict__ Kph,
                                          const _Float16* __restrict__ Vph,
                                          const _Float16* __restrict__ fh,
                                          const half8 qa[4], int lane,
                                          int off, int seam, int nch,
                                          floatx16& o0, floatx16& o1, floatx16& lacc) {
  const int  half_ = lane >> 5;
  const int  c     = lane & 31;
  const bool hb    = half_ != 0;
  auto kbof = [&](int ci) { return ci * 32 + ((ci >= seam) ? off : 0); };

  half8 kf[4];
  const int kb0 = kbof(0);
#pragma unroll
  for (int ks = 0; ks < 4; ++ks)
    kf[ks] = *(const half8*)&Kph[(size_t)((ks * 2 + half_) * R_TOT + kb0 + c) * 8];
  floatx16 s = zero16();
#pragma unroll
  for (int ks = 0; ks < 4; ++ks)
    s = __builtin_amdgcn_mfma_f32_32x32x16_f16(kf[ks], qa[ks], s, 0, 0, 0);
  const int kb1 = kbof(nch > 1 ? 1 : 0);
#pragma unroll
  for (int ks = 0; ks < 4; ++ks)
    kf[ks] = *(const half8*)&Kph[(size_t)((ks * 2 + half_) * R_TOT + kb1 + c) * 8];

  for (int ci = 0; ci < nch; ++ci) {
    const int kb = kbof(ci);
    // V + f loads for current chunk (independent; issue early)
    const int xb = kb >> 3;
    half8 vA0 = *(const half8*)&Vph[(size_t)((xb + half_) * 64 + c) * 8];
    half8 vA1 = *(const half8*)&Vph[(size_t)((xb + 2 + half_) * 64 + c) * 8];
    half8 vB0 = *(const half8*)&Vph[(size_t)((xb + half_) * 64 + 32 + c) * 8];
    half8 vB1 = *(const half8*)&Vph[(size_t)((xb + 2 + half_) * 64 + 32 + c) * 8];
    half8 f0 = *(const half8*)&fh[kb + half_ * 8];
    half8 f1 = *(const half8*)&fh[kb + 16 + half_ * 8];
    // next chunk's QK (kf prefetched last iteration; branchless clamp on tail)
    floatx16 sn = zero16();
#pragma unroll
    for (int ks = 0; ks < 4; ++ks)
      sn = __builtin_amdgcn_mfma_f32_32x32x16_f16(kf[ks], qa[ks], sn, 0, 0, 0);
    const int kbn = kbof(ci + 2 < nch ? ci + 2 : nch - 1);
#pragma unroll
    for (int ks = 0; ks < 4; ++ks)
      kf[ks] = *(const half8*)&Kph[(size_t)((ks * 2 + half_) * R_TOT + kbn + c) * 8];
    // exp chain on current s (VALU, overlaps sn MFMAs)
    int pk[8];
#pragma unroll
    for (int i = 0; i < 8; ++i) {
      float e0 = __builtin_amdgcn_exp2f(s[2 * i]);
      float e1 = __builtin_amdgcn_exp2f(s[2 * i + 1]);
      pk[i] = pk_f16x2(e0, e1);
    }
    int sw[8];
#pragma unroll
    for (int i = 0; i < 8; ++i) sw[i] = __shfl_xor(pk[i], 32);
    int4 bi0, bi1;
    bi0.x = hb ? sw[2] : pk[0];  bi0.y = hb ? sw[3] : pk[1];
    bi0.z = hb ? pk[2] : sw[0];  bi0.w = hb ? pk[3] : sw[1];
    bi1.x = hb ? sw[6] : pk[4];  bi1.y = hb ? sw[7] : pk[5];
    bi1.z = hb ? pk[6] : sw[4];  bi1.w = hb ? pk[7] : sw[5];
    half8 b0 = __builtin_bit_cast(half8, bi0);
    half8 b1 = __builtin_bit_cast(half8, bi1);
    lacc = __builtin_amdgcn_mfma_f32_32x32x16_f16(f0, b0, lacc, 0, 0, 0);
    lacc = __builtin_amdgcn_mfma_f32_32x32x16_f16(f1, b1, lacc, 0, 0, 0);
    o0 = __builtin_amdgcn_mfma_f32_32x32x16_f16(vA0, b0, o0, 0, 0, 0);
    o0 = __builtin_amdgcn_mfma_f32_32x32x16_f16(vA1, b1, o0, 0, 0, 0);
    o1 = __builtin_amdgcn_mfma_f32_32x32x16_f16(vB0, b0, o1, 0, 0, 0);
    o1 = __builtin_amdgcn_mfma_f32_32x32x16_f16(vB1, b1, o1, 0, 0, 0);
    s = sn;
  }
}

// ---------------- stage 2: fused attention (glob blocks first, local backfills) ----------------
__global__ __launch_bounds__(256) void attn_k(char* __restrict__ ws) {
  const int wave = threadIdx.x >> 6, lane = threadIdx.x & 63;
  const int bx = blockIdx.x;
  const _Float16* fh = (const _Float16*)(ws + OFF_FH);
  const int half_ = lane >> 5, c = lane & 31;
  if (bx < NSPL * H_NUM) {
    // ---- global attention partials: long blocks (26 chunks) dispatched first
    const int h = bx / NSPL, spl = bx % NSPL;
    const int qbase = wave * 32;
    const _Float16* Qph = (const _Float16*)(ws + OFF_QP) + (size_t)h * 8 * R_TOT * 8;
    const _Float16* Kph = (const _Float16*)(ws + OFF_KP) + (size_t)h * 8 * R_TOT * 8;
    const _Float16* Vph = (const _Float16*)(ws + OFF_VP) + (size_t)h * XBLK * 64 * 8;
    half8 qa[4];
#pragma unroll
    for (int ks = 0; ks < 4; ++ks)
      qa[ks] = *(const half8*)&Qph[(size_t)((ks * 2 + half_) * R_TOT + qbase + c) * 8];
    floatx16 o0 = zero16(), o1 = zero16(), l = zero16();
    attn_core(Kph, Vph, fh, qa, lane, spl * SPLW, 0, SPLW / 32, o0, o1, l);
    float* Og = (float*)(ws + OFF_OG);
    float* Lg = (float*)(ws + OFF_LG);
    const int q = qbase + c;
#pragma unroll
    for (int g = 0; g < 4; ++g) {
      float4 fa, fb;
      fa.x = o0[4 * g]; fa.y = o0[4 * g + 1]; fa.z = o0[4 * g + 2]; fa.w = o0[4 * g + 3];
      fb.x = o1[4 * g]; fb.y = o1[4 * g + 1]; fb.z = o1[4 * g + 2]; fb.w = o1[4 * g + 3];
      *(float4*)&Og[((size_t)(spl * H_NUM + h) * 128 + q) * 64 + 8 * g + 4 * half_] = fa;
      *(float4*)&Og[((size_t)(spl * H_NUM + h) * 128 + q) * 64 + 32 + 8 * g + 4 * half_] = fb;
    }
    if (half_ == 0) Lg[(spl * H_NUM + h) * 128 + q] = l[0];
  } else {
    // ---- local attention: keys = global(128) + own block(512), 20 chunks
    const int t = bx - NSPL * H_NUM;
    const int h = t >> 6, blk = (t >> 2) & 15, qg = t & 3;
    const int qbase = G_LEN + blk * BS_LEN + qg * 128 + wave * 32;
    const _Float16* Qph = (const _Float16*)(ws + OFF_QP) + (size_t)h * 8 * R_TOT * 8;
    const _Float16* Kph = (const _Float16*)(ws + OFF_KP) + (size_t)h * 8 * R_TOT * 8;
    const _Float16* Vph = (const _Float16*)(ws + OFF_VP) + (size_t)h * XBLK * 64 * 8;
    half8 qa[4];
#pragma unroll
    for (int ks = 0; ks < 4; ++ks)
      qa[ks] = *(const half8*)&Qph[(size_t)((ks * 2 + half_) * R_TOT + qbase + c) * 8];
    floatx16 o0 = zero16(), o1 = zero16(), l = zero16();
    // ci<4: global keys (kb=ci*32); ci>=4: kb = ci*32 + blk*512
    attn_core(Kph, Vph, fh, qa, lane, blk * BS_LEN, 4, 20, o0, o1, l);
    _Float16* AOp = (_Float16*)(ws + OFF_AOP);
    const float inv = 1.0f / l[0];
    const int m = qbase + c;
#pragma unroll
    for (int g = 0; g < 4; ++g) {
      half4 ha, hc;
#pragma unroll
      for (int i = 0; i < 4; ++i) {
        ha[i] = (_Float16)(o0[4 * g + i] * inv);
        hc[i] = (_Float16)(o1[4 * g + i] * inv);
      }
      *(half4*)&AOp[((size_t)(h * 8 + g) * R_TOT + m) * 8 + 4 * half_] = ha;
      *(half4*)&AOp[((size_t)(h * 8 + 4 + g) * R_TOT + m) * 8 + 4 * half_] = hc;
    }
  }
}

// ---------------- stage 2c: combine global partials ----------------
__global__ void combine_k(char* __restrict__ ws) {
  int idx = blockIdx.x * 256 + threadIdx.x;   // H*128*64 = 131072
  int h = idx >> 13, rem = idx & 8191, q = rem >> 6, d = rem & 63;
  const float* Og = (const float*)(ws + OFF_OG);
  const float* Lg = (const float*)(ws + OFF_LG);
  float o = 0.0f, l = 0.0f;
#pragma unroll
  for (int s = 0; s < NSPL; ++s) {
    o += Og[(size_t)((s * H_NUM + h) * 128 + q) * 64 + d];
    l += Lg[(s * H_NUM + h) * 128 + q];
  }
  int n = h * 64 + d;
  ((_Float16*)(ws + OFF_AOP))[((size_t)(n >> 3) * R_TOT + q) * 8 + (n & 7)] = (_Float16)(o / l);
}

// ---------------- stage 3: output projection -> d_out (fp32, float4 stores) ----------------
__global__ __launch_bounds__(256) void out_gemm_k(char* __restrict__ ws, float* __restrict__ dout) {
  __shared__ __align__(16) _Float16 lds[2 * 8 * 128 * 8];
  const int m0 = blockIdx.y * 128;
  const int n0 = blockIdx.x * 128;
  floatx4 acc[4][4];
#pragma unroll
  for (int a = 0; a < 4; ++a)
#pragma unroll
    for (int b = 0; b < 4; ++b) acc[a][b] = zero4();
  gemm_tile((const _Float16*)(ws + OFF_AOP),
            (const _Float16*)(ws + OFF_WP + 3 * (size_t)SZ_WP1), m0, n0, lds, acc);
  const int lane = threadIdx.x & 63, wave = threadIdx.x >> 6;
  const int quad = lane >> 4, l16 = lane & 15;
  const int wm = (wave >> 1) * 64, wn = (wave & 1) * 64;
#pragma unroll
  for (int mt = 0; mt < 4; ++mt)
#pragma unroll
    for (int nt = 0; nt < 4; ++nt) {
      int m  = m0 + wm + mt * 16 + l16;
      int nb = n0 + wn + nt * 16 + quad * 4;
      float4 f4;
      f4.x = acc[mt][nt][0]; f4.y = acc[mt][nt][1];
      f4.z = acc[mt][nt][2]; f4.w = acc[mt][nt][3];
      float* p = (m < G_LEN) ? (dout + (size_t)S_LEN * E_DIM + (size_t)m * E_DIM + nb)
                             : (dout + (size_t)(m - G_LEN) * E_DIM + nb);
      *(float4*)p = f4;
    }
}

extern "C" void kernel_launch(void* const* d_in, const int* in_sizes, int n_in,
                              void* d_out, int out_size, void* d_ws, size_t ws_size,
                              hipStream_t stream) {
  const float* tok  = (const float*)d_in[0];
  const float* glob = (const float*)d_in[1];
  const float* mask = (const float*)d_in[2];
  const float* Wq   = (const float*)d_in[3];
  const float* Wk   = (const float*)d_in[4];
  const float* Wv   = (const float*)d_in[5];
  const float* Wo   = (const float*)d_in[6];
  char*  ws   = (char*)d_ws;
  float* dout = (float*)d_out;

  prep_k<<<dim3(1040 + 2081), dim3(256), 0, stream>>>(tok, glob, Wq, Wk, Wv, Wo, mask, ws);
  qkv_gemm_k<<<dim3(8, 65), dim3(256), 0, stream>>>(ws, 0);
  qkv_gemm_k<<<dim3(8, 65), dim3(256), 0, stream>>>(ws, 1);
  qkv_gemm_k<<<dim3(8, 65), dim3(256), 0, stream>>>(ws, 2);
  attn_k<<<dim3(NSPL * H_NUM + 1024), dim3(256), 0, stream>>>(ws);
  combine_k<<<dim3(512), dim3(256), 0, stream>>>(ws);
  out_gemm_k<<<dim3(8, 65), dim3(256), 0, stream>>>(ws, dout);
}

// Round 9
// 255.976 us; speedup vs baseline: 1.0898x; 1.0898x over previous
//
#include <hip/hip_runtime.h>
#include <stdint.h>

#define S_LEN  8192
#define G_LEN  128
#define E_DIM  1024
#define H_NUM  16
#define BS_LEN 512
#define R_TOT  8320          // G + S total rows
#define KBLK   128           // 1024/8 k-blocks
#define XBLK   1040          // R_TOT/8
#define NSPL   10            // global-attn key splits
#define SPLW   832           // keys per split (26 chunks of 32)

typedef _Float16 half8    __attribute__((ext_vector_type(8)));
typedef _Float16 half4    __attribute__((ext_vector_type(4)));
typedef float    floatx4  __attribute__((ext_vector_type(4)));
typedef float    floatx16 __attribute__((ext_vector_type(16)));

// Q scale = D^-0.5 * log2(e): exp(x) computed as exp2(x*log2e) with log2e folded into Q
#define QSCALE 0.18033688011112042f

// ---- workspace layout (bytes) ----
#define OFF_XP   0
#define OFF_AOP  0            // reuse: Xp dead after QKV GEMMs
#define OFF_WP   17039360
#define SZ_WP1   2097152
#define OFF_QP   25427968
#define OFF_KP   42467328
#define OFF_VP   59506688
#define OFF_FH   76546048     // f16 exp(mask) per key row, R_TOT entries
#define OFF_OG   76579328
#define OFF_LG   81822208

__device__ __forceinline__ floatx16 zero16() {
  floatx16 v;
#pragma unroll
  for (int i = 0; i < 16; ++i) v[i] = 0.0f;
  return v;
}
__device__ __forceinline__ floatx4 zero4() {
  floatx4 v;
#pragma unroll
  for (int i = 0; i < 4; ++i) v[i] = 0.0f;
  return v;
}

__device__ __forceinline__ void gl_lds16(const void* g, void* l) {
  __builtin_amdgcn_global_load_lds(
      (const __attribute__((address_space(1))) void*)g,
      (__attribute__((address_space(3))) void*)l, 16, 0, 0);
}

__device__ __forceinline__ int pk_f16x2(float a, float b) {
  return __builtin_bit_cast(int, __builtin_amdgcn_cvt_pkrtz(a, b));
}

// ---------------- stage 0: fused prep — pack X (LDS transpose) + pack W + fh ----------------
__global__ __launch_bounds__(256) void prep_k(const float* __restrict__ tok,
                                              const float* __restrict__ glob,
                                              const float* __restrict__ Wq,
                                              const float* __restrict__ Wk,
                                              const float* __restrict__ Wv,
                                              const float* __restrict__ Wo,
                                              const float* __restrict__ mask,
                                              char* __restrict__ ws) {
  __shared__ __align__(16) _Float16 tile[64 * 132];
  const int bx  = blockIdx.x;
  const int tid = threadIdx.x;
  if (bx < 1040) {
    const int r0 = (bx >> 3) * 64;
    const int c0 = (bx & 7) * 128;
#pragma unroll
    for (int kk = 0; kk < 8; ++kk) {
      int f   = tid + kk * 256;
      int row = f >> 5;
      int c4  = (f & 31) * 4;
      int r   = r0 + row;
      const float* src = (r < G_LEN) ? glob + (size_t)r * E_DIM
                                     : tok + (size_t)(r - G_LEN) * E_DIM;
      float4 v = *(const float4*)&src[c0 + c4];
      half4 h;
      h[0] = (_Float16)v.x; h[1] = (_Float16)v.y; h[2] = (_Float16)v.z; h[3] = (_Float16)v.w;
      *(half4*)&tile[row * 132 + c4] = h;
    }
    __syncthreads();
    _Float16* Xp = (_Float16*)(ws + OFF_XP);
#pragma unroll
    for (int uu = 0; uu < 4; ++uu) {
      int u    = tid + uu * 256;
      int kb_l = u >> 6;
      int row  = u & 63;
      half4 a = *(const half4*)&tile[row * 132 + kb_l * 8];
      half4 b = *(const half4*)&tile[row * 132 + kb_l * 8 + 4];
      half8 o;
      o[0] = a[0]; o[1] = a[1]; o[2] = a[2]; o[3] = a[3];
      o[4] = b[0]; o[5] = b[1]; o[6] = b[2]; o[7] = b[3];
      int kb = (c0 >> 3) + kb_l;
      *(half8*)&Xp[((size_t)kb * R_TOT + r0 + row) * 8] = o;
    }
  } else {
    int t = (bx - 1040) * 256 + tid;
    const int NW = 4 * KBLK * 1024;
    if (t < NW) {
      int w   = t >> 17;
      int rem = t & 131071;
      int kb  = rem >> 10;
      int n   = rem & 1023;
      const float* W = (w == 0) ? Wq : (w == 1) ? Wk : (w == 2) ? Wv : Wo;
      half8 v;
#pragma unroll
      for (int j = 0; j < 8; ++j)
        v[j] = (_Float16)W[(size_t)(kb * 8 + j) * 1024 + n];
      *(half8*)(ws + OFF_WP + (size_t)w * SZ_WP1 + (size_t)(kb * 1024 + n) * 16) = v;
    } else {
      int t2 = t - NW;
      if (t2 < R_TOT) {
        _Float16* fh = (_Float16*)(ws + OFF_FH);
        float m = (t2 < G_LEN) ? 0.0f : mask[t2 - G_LEN];
        fh[t2] = (_Float16)__expf(m);
      }
    }
  }
}

// ---------------- shared GEMM mainloop (R6 dual-LDS, swapped mfma) ----------------
// acc rows = 4 consecutive n (quad*4+r), lane l16 = m.
__device__ __forceinline__ void gemm_tile(const _Float16* __restrict__ Ap,
                                          const _Float16* __restrict__ Bp,
                                          int m0, int n0, _Float16* lds,
                                          floatx4 acc[4][4]) {
  const int tid  = threadIdx.x;
  const int wave = tid >> 6;
  const int lane = tid & 63;
  const int quad = lane >> 4;
  const int l16  = lane & 15;
  _Float16* As = lds;
  _Float16* Bs = lds + 8 * 128 * 8;
  const int wm = (wave >> 1) * 64;
  const int wn = (wave & 1) * 64;
  for (int step = 0; step < 16; ++step) {
#pragma unroll
    for (int ui = 0; ui < 8; ++ui) {
      const int u   = wave * 8 + ui;   // 32 units: 16 A, 16 B
      const int isB = u >> 4;
      const int vv  = u & 15;
      const int kb  = vv >> 1;
      const int rh  = vv & 1;
      const _Float16* src =
          isB ? Bp + (size_t)((step * 8 + kb) * 1024 + n0 + rh * 64 + lane) * 8
              : Ap + (size_t)((step * 8 + kb) * R_TOT + m0 + rh * 64 + lane) * 8;
      _Float16* dst = (isB ? Bs : As) + (kb * 128 + rh * 64) * 8;
      gl_lds16(src, dst);
    }
    __syncthreads();
#pragma unroll
    for (int kk = 0; kk < 2; ++kk) {
      half8 af[4], bf[4];
#pragma unroll
      for (int mt = 0; mt < 4; ++mt)
        af[mt] = *(const half8*)(As + ((kk * 4 + quad) * 128 + wm + mt * 16 + l16) * 8);
#pragma unroll
      for (int nt = 0; nt < 4; ++nt)
        bf[nt] = *(const half8*)(Bs + ((kk * 4 + quad) * 128 + wn + nt * 16 + l16) * 8);
#pragma unroll
      for (int mt = 0; mt < 4; ++mt)
#pragma unroll
        for (int nt = 0; nt < 4; ++nt)
          acc[mt][nt] = __builtin_amdgcn_mfma_f32_16x16x32_f16(bf[nt], af[mt], acc[mt][nt], 0, 0, 0);
    }
    __syncthreads();
  }
}

// ---------------- stage 1: fused Q/K/V projections (single dispatch) ----------------
__global__ __launch_bounds__(256) void qkv_gemm_k(char* __restrict__ ws) {
  __shared__ __align__(16) _Float16 lds[2 * 8 * 128 * 8];   // 32 KB
  const int z  = blockIdx.x >> 3;                           // 0=Q 1=K 2=V
  const int n0 = (blockIdx.x & 7) * 128;
  const int m0 = blockIdx.y * 128;
  floatx4 acc[4][4];
#pragma unroll
  for (int a = 0; a < 4; ++a)
#pragma unroll
    for (int b = 0; b < 4; ++b) acc[a][b] = zero4();
  gemm_tile((const _Float16*)(ws + OFF_XP),
            (const _Float16*)(ws + OFF_WP + (size_t)z * SZ_WP1), m0, n0, lds, acc);

  const int lane = threadIdx.x & 63, wave = threadIdx.x >> 6;
  const int quad = lane >> 4, l16 = lane & 15;
  const int wm = (wave >> 1) * 64, wn = (wave & 1) * 64;
  if (z < 2) {
    _Float16* dst = (_Float16*)(ws + (z == 0 ? OFF_QP : OFF_KP));
    const float scale = (z == 0) ? QSCALE : 1.0f;
#pragma unroll
    for (int mt = 0; mt < 4; ++mt)
#pragma unroll
      for (int nt = 0; nt < 4; ++nt) {
        int m  = m0 + wm + mt * 16 + l16;
        int nb = n0 + wn + nt * 16 + quad * 4;
        half4 h;
#pragma unroll
        for (int r = 0; r < 4; ++r) h[r] = (_Float16)(acc[mt][nt][r] * scale);
        int db = (nb >> 6) * 8 + ((nb & 63) >> 3);
        *(half4*)&dst[((size_t)db * R_TOT + m) * 8 + (nb & 7)] = h;
      }
  } else {
    _Float16* dst = (_Float16*)(ws + OFF_VP);
    const _Float16* fh = (const _Float16*)(ws + OFF_FH);
#pragma unroll
    for (int mt = 0; mt < 4; ++mt) {
      int m = m0 + wm + mt * 16 + l16;
      float fhm = (float)fh[m];
#pragma unroll
      for (int nt = 0; nt < 4; ++nt) {
        int nl = n0 + wn + nt * 16 + quad * 4;
#pragma unroll
        for (int r = 0; r < 4; ++r) {
          int n = nl + r;
          dst[(((size_t)(n >> 6) * XBLK + (m >> 3)) * 64 + (n & 63)) * 8 + (m & 7)] =
              (_Float16)(acc[mt][nt][r] * fhm);
        }
      }
    }
  }
}

// ---------------- attention core: K/V chunk staged in LDS, shared by all 4 waves ----------------
// LDS chunk buffer (8 KB): K = [db 0..7][key 0..31][8] (4 KB) then V = 4 KB contiguous
// ([xbl 0..3][d 0..63][8]). Double-buffered, distance-1 async prefetch, 1 barrier/chunk.
__device__ __forceinline__ void attn_chunks_lds(const _Float16* __restrict__ Kph,
                                                const _Float16* __restrict__ Vph,
                                                const _Float16* __restrict__ fh,
                                                const half8 qa[4], int wave, int lane,
                                                int off, int seam, int nch,
                                                _Float16 (* __restrict__ kv)[4096],
                                                floatx16& o0, floatx16& o1, floatx16& lacc) {
  const int  half_ = lane >> 5;
  const int  c     = lane & 31;
  const bool hb    = half_ != 0;
  auto kbof = [&](int ci) { return ci * 32 + ((ci >= seam) ? off : 0); };
  auto stage = [&](int buf, int kb) {
    if (wave < 2) {
      // K: 4 KB as 4 × 1 KB units (db-pairs); waves 0,1 take 2 each
#pragma unroll
      for (int j = 0; j < 2; ++j) {
        const int u2  = wave * 2 + j;            // db-pair 0..3
        const int db  = u2 * 2 + (lane >> 5);
        const int key = lane & 31;
        gl_lds16(&Kph[((size_t)db * R_TOT + kb + key) * 8], &kv[buf][u2 * 512]);
      }
    } else {
      // V: 4 KB contiguous as 4 × 1 KB units; waves 2,3 take 2 each
#pragma unroll
      for (int j = 0; j < 2; ++j) {
        const int q4 = (wave - 2) * 2 + j;       // quarter 0..3
        gl_lds16(&Vph[(size_t)((kb >> 3) + q4) * 512 + (size_t)lane * 8],
                 &kv[buf][2048 + q4 * 512]);
      }
    }
  };

  stage(0, kbof(0));
  __syncthreads();
  for (int ci = 0; ci < nch; ++ci) {
    const int cur = ci & 1;
    if (ci + 1 < nch) stage(cur ^ 1, kbof(ci + 1));
    const _Float16* Kb = kv[cur];
    const _Float16* Vb = kv[cur] + 2048;
    const int kb = kbof(ci);
    // QK^T (S^T layout: lane=query col, regs=key rows)
    floatx16 s = zero16();
#pragma unroll
    for (int ks = 0; ks < 4; ++ks) {
      half8 kfr = *(const half8*)&Kb[((ks * 2 + half_) * 32 + c) * 8];
      s = __builtin_amdgcn_mfma_f32_32x32x16_f16(kfr, qa[ks], s, 0, 0, 0);
    }
    // exp + pack + cross-half exchange (builds PV B-fragments in-register)
    int pk[8];
#pragma unroll
    for (int i = 0; i < 8; ++i) {
      float e0 = __builtin_amdgcn_exp2f(s[2 * i]);
      float e1 = __builtin_amdgcn_exp2f(s[2 * i + 1]);
      pk[i] = pk_f16x2(e0, e1);
    }
    int sw[8];
#pragma unroll
    for (int i = 0; i < 8; ++i) sw[i] = __shfl_xor(pk[i], 32);
    int4 bi0, bi1;
    bi0.x = hb ? sw[2] : pk[0];  bi0.y = hb ? sw[3] : pk[1];
    bi0.z = hb ? pk[2] : sw[0];  bi0.w = hb ? pk[3] : sw[1];
    bi1.x = hb ? sw[6] : pk[4];  bi1.y = hb ? sw[7] : pk[5];
    bi1.z = hb ? pk[6] : sw[4];  bi1.w = hb ? pk[7] : sw[5];
    half8 b0 = __builtin_bit_cast(half8, bi0);
    half8 b1 = __builtin_bit_cast(half8, bi1);
    // l accumulation (A-frag = f = exp(mask), row-independent)
    half8 f0 = *(const half8*)&fh[kb + half_ * 8];
    half8 f1 = *(const half8*)&fh[kb + 16 + half_ * 8];
    lacc = __builtin_amdgcn_mfma_f32_32x32x16_f16(f0, b0, lacc, 0, 0, 0);
    lacc = __builtin_amdgcn_mfma_f32_32x32x16_f16(f1, b1, lacc, 0, 0, 0);
    // PV (A-frag = V' d-rows from LDS)
    half8 vA0 = *(const half8*)&Vb[(half_ * 64 + c) * 8];
    half8 vA1 = *(const half8*)&Vb[((2 + half_) * 64 + c) * 8];
    half8 vB0 = *(const half8*)&Vb[(half_ * 64 + 32 + c) * 8];
    half8 vB1 = *(const half8*)&Vb[((2 + half_) * 64 + 32 + c) * 8];
    o0 = __builtin_amdgcn_mfma_f32_32x32x16_f16(vA0, b0, o0, 0, 0, 0);
    o0 = __builtin_amdgcn_mfma_f32_32x32x16_f16(vA1, b1, o0, 0, 0, 0);
    o1 = __builtin_amdgcn_mfma_f32_32x32x16_f16(vB0, b0, o1, 0, 0, 0);
    o1 = __builtin_amdgcn_mfma_f32_32x32x16_f16(vB1, b1, o1, 0, 0, 0);
    __syncthreads();   // all waves done reading cur; next chunk's DMA drained
  }
}

// ---------------- stage 2: fused attention (glob blocks first, local backfills) ----------------
__global__ __launch_bounds__(256) void attn_k(char* __restrict__ ws) {
  __shared__ __align__(16) _Float16 kv[2][4096];   // 16 KB: 2 × (K 4KB + V 4KB)
  const int wave = threadIdx.x >> 6, lane = threadIdx.x & 63;
  const int bx = blockIdx.x;
  const _Float16* fh = (const _Float16*)(ws + OFF_FH);
  const int half_ = lane >> 5, c = lane & 31;
  if (bx < NSPL * H_NUM) {
    // ---- global attention partials: long blocks (26 chunks) dispatched first
    const int h = bx / NSPL, spl = bx % NSPL;
    const int qbase = wave * 32;
    const _Float16* Qph = (const _Float16*)(ws + OFF_QP) + (size_t)h * 8 * R_TOT * 8;
    const _Float16* Kph = (const _Float16*)(ws + OFF_KP) + (size_t)h * 8 * R_TOT * 8;
    const _Float16* Vph = (const _Float16*)(ws + OFF_VP) + (size_t)h * XBLK * 64 * 8;
    half8 qa[4];
#pragma unroll
    for (int ks = 0; ks < 4; ++ks)
      qa[ks] = *(const half8*)&Qph[(size_t)((ks * 2 + half_) * R_TOT + qbase + c) * 8];
    floatx16 o0 = zero16(), o1 = zero16(), l = zero16();
    attn_chunks_lds(Kph, Vph, fh, qa, wave, lane, spl * SPLW, 0, SPLW / 32, kv, o0, o1, l);
    float* Og = (float*)(ws + OFF_OG);
    float* Lg = (float*)(ws + OFF_LG);
    const int q = qbase + c;
#pragma unroll
    for (int g = 0; g < 4; ++g) {
      float4 fa, fb;
      fa.x = o0[4 * g]; fa.y = o0[4 * g + 1]; fa.z = o0[4 * g + 2]; fa.w = o0[4 * g + 3];
      fb.x = o1[4 * g]; fb.y = o1[4 * g + 1]; fb.z = o1[4 * g + 2]; fb.w = o1[4 * g + 3];
      *(float4*)&Og[((size_t)(spl * H_NUM + h) * 128 + q) * 64 + 8 * g + 4 * half_] = fa;
      *(float4*)&Og[((size_t)(spl * H_NUM + h) * 128 + q) * 64 + 32 + 8 * g + 4 * half_] = fb;
    }
    if (half_ == 0) Lg[(spl * H_NUM + h) * 128 + q] = l[0];
  } else {
    // ---- local attention: keys = global(128) + own block(512), 20 chunks
    const int t = bx - NSPL * H_NUM;
    const int h = t >> 6, blk = (t >> 2) & 15, qg = t & 3;
    const int qbase = G_LEN + blk * BS_LEN + qg * 128 + wave * 32;
    const _Float16* Qph = (const _Float16*)(ws + OFF_QP) + (size_t)h * 8 * R_TOT * 8;
    const _Float16* Kph = (const _Float16*)(ws + OFF_KP) + (size_t)h * 8 * R_TOT * 8;
    const _Float16* Vph = (const _Float16*)(ws + OFF_VP) + (size_t)h * XBLK * 64 * 8;
    half8 qa[4];
#pragma unroll
    for (int ks = 0; ks < 4; ++ks)
      qa[ks] = *(const half8*)&Qph[(size_t)((ks * 2 + half_) * R_TOT + qbase + c) * 8];
    floatx16 o0 = zero16(), o1 = zero16(), l = zero16();
    // ci<4: global keys (kb=ci*32); ci>=4: kb = ci*32 + blk*512
    attn_chunks_lds(Kph, Vph, fh, qa, wave, lane, blk * BS_LEN, 4, 20, kv, o0, o1, l);
    _Float16* AOp = (_Float16*)(ws + OFF_AOP);
    const float inv = 1.0f / l[0];
    const int m = qbase + c;
#pragma unroll
    for (int g = 0; g < 4; ++g) {
      half4 ha, hc;
#pragma unroll
      for (int i = 0; i < 4; ++i) {
        ha[i] = (_Float16)(o0[4 * g + i] * inv);
        hc[i] = (_Float16)(o1[4 * g + i] * inv);
      }
      *(half4*)&AOp[((size_t)(h * 8 + g) * R_TOT + m) * 8 + 4 * half_] = ha;
      *(half4*)&AOp[((size_t)(h * 8 + 4 + g) * R_TOT + m) * 8 + 4 * half_] = hc;
    }
  }
}

// ---------------- stage 2c: combine global partials ----------------
__global__ void combine_k(char* __restrict__ ws) {
  int idx = blockIdx.x * 256 + threadIdx.x;   // H*128*64 = 131072
  int h = idx >> 13, rem = idx & 8191, q = rem >> 6, d = rem & 63;
  const float* Og = (const float*)(ws + OFF_OG);
  const float* Lg = (const float*)(ws + OFF_LG);
  float o = 0.0f, l = 0.0f;
#pragma unroll
  for (int s = 0; s < NSPL; ++s) {
    o += Og[(size_t)((s * H_NUM + h) * 128 + q) * 64 + d];
    l += Lg[(s * H_NUM + h) * 128 + q];
  }
  int n = h * 64 + d;
  ((_Float16*)(ws + OFF_AOP))[((size_t)(n >> 3) * R_TOT + q) * 8 + (n & 7)] = (_Float16)(o / l);
}

// ---------------- stage 3: output projection -> d_out (fp32, float4 stores) ----------------
__global__ __launch_bounds__(256) void out_gemm_k(char* __restrict__ ws, float* __restrict__ dout) {
  __shared__ __align__(16) _Float16 lds[2 * 8 * 128 * 8];
  const int m0 = blockIdx.y * 128;
  const int n0 = blockIdx.x * 128;
  floatx4 acc[4][4];
#pragma unroll
  for (int a = 0; a < 4; ++a)
#pragma unroll
    for (int b = 0; b < 4; ++b) acc[a][b] = zero4();
  gemm_tile((const _Float16*)(ws + OFF_AOP),
            (const _Float16*)(ws + OFF_WP + 3 * (size_t)SZ_WP1), m0, n0, lds, acc);
  const int lane = threadIdx.x & 63, wave = threadIdx.x >> 6;
  const int quad = lane >> 4, l16 = lane & 15;
  const int wm = (wave >> 1) * 64, wn = (wave & 1) * 64;
#pragma unroll
  for (int mt = 0; mt < 4; ++mt)
#pragma unroll
    for (int nt = 0; nt < 4; ++nt) {
      int m  = m0 + wm + mt * 16 + l16;
      int nb = n0 + wn + nt * 16 + quad * 4;
      float4 f4;
      f4.x = acc[mt][nt][0]; f4.y = acc[mt][nt][1];
      f4.z = acc[mt][nt][2]; f4.w = acc[mt][nt][3];
      float* p = (m < G_LEN) ? (dout + (size_t)S_LEN * E_DIM + (size_t)m * E_DIM + nb)
                             : (dout + (size_t)(m - G_LEN) * E_DIM + nb);
      *(float4*)p = f4;
    }
}

extern "C" void kernel_launch(void* const* d_in, const int* in_sizes, int n_in,
                              void* d_out, int out_size, void* d_ws, size_t ws_size,
                              hipStream_t stream) {
  const float* tok  = (const float*)d_in[0];
  const float* glob = (const float*)d_in[1];
  const float* mask = (const float*)d_in[2];
  const float* Wq   = (const float*)d_in[3];
  const float* Wk   = (const float*)d_in[4];
  const float* Wv   = (const float*)d_in[5];
  const float* Wo   = (const float*)d_in[6];
  char*  ws   = (char*)d_ws;
  float* dout = (float*)d_out;

  prep_k<<<dim3(1040 + 2081), dim3(256), 0, stream>>>(tok, glob, Wq, Wk, Wv, Wo, mask, ws);
  qkv_gemm_k<<<dim3(24, 65), dim3(256), 0, stream>>>(ws);
  attn_k<<<dim3(NSPL * H_NUM + 1024), dim3(256), 0, stream>>>(ws);
  combine_k<<<dim3(512), dim3(256), 0, stream>>>(ws);
  out_gemm_k<<<dim3(8, 65), dim3(256), 0, stream>>>(ws, dout);
}

// Round 11
// 250.833 us; speedup vs baseline: 1.1121x; 1.0205x over previous
//
#include <hip/hip_runtime.h>
#include <stdint.h>

#define S_LEN  8192
#define G_LEN  128
#define E_DIM  1024
#define H_NUM  16
#define BS_LEN 512
#define R_TOT  8320          // G + S total rows
#define KBLK   128           // 1024/8 k-blocks
#define XBLK   1040          // R_TOT/8
#define NSPL   10            // global-attn key splits
#define SPLW   832           // keys per split (26 chunks of 32)

typedef _Float16 half8    __attribute__((ext_vector_type(8)));
typedef _Float16 half4    __attribute__((ext_vector_type(4)));
typedef float    floatx4  __attribute__((ext_vector_type(4)));
typedef float    floatx16 __attribute__((ext_vector_type(16)));

#define QSCALE 0.18033688011112042f   // D^-0.5 * log2(e)

// ---- workspace layout (bytes) ----
#define OFF_XP   0
#define OFF_AOP  0            // reuse: Xp dead after QKV GEMMs
#define OFF_WP   17039360
#define SZ_WP1   2097152
#define OFF_QP   25427968
#define OFF_KP   42467328
#define OFF_VP   59506688
#define OFF_FH   76546048
#define OFF_OG   76579328
#define OFF_LG   81822208

__device__ __forceinline__ floatx16 zero16() {
  floatx16 v;
#pragma unroll
  for (int i = 0; i < 16; ++i) v[i] = 0.0f;
  return v;
}
__device__ __forceinline__ floatx4 zero4() {
  floatx4 v;
#pragma unroll
  for (int i = 0; i < 4; ++i) v[i] = 0.0f;
  return v;
}

__device__ __forceinline__ void gl_lds16(const void* g, void* l) {
  __builtin_amdgcn_global_load_lds(
      (const __attribute__((address_space(1))) void*)g,
      (__attribute__((address_space(3))) void*)l, 16, 0, 0);
}

__device__ __forceinline__ int pk_f16x2(float a, float b) {
  return __builtin_bit_cast(int, __builtin_amdgcn_cvt_pkrtz(a, b));
}

// ---------------- stage 0: fused prep — pack X (LDS transpose) + pack W + fh ----------------
__global__ __launch_bounds__(256) void prep_k(const float* __restrict__ tok,
                                              const float* __restrict__ glob,
                                              const float* __restrict__ Wq,
                                              const float* __restrict__ Wk,
                                              const float* __restrict__ Wv,
                                              const float* __restrict__ Wo,
                                              const float* __restrict__ mask,
                                              char* __restrict__ ws) {
  __shared__ __align__(16) _Float16 tile[64 * 132];
  const int bx  = blockIdx.x;
  const int tid = threadIdx.x;
  if (bx < 1040) {
    const int r0 = (bx >> 3) * 64;
    const int c0 = (bx & 7) * 128;
#pragma unroll
    for (int kk = 0; kk < 8; ++kk) {
      int f   = tid + kk * 256;
      int row = f >> 5;
      int c4  = (f & 31) * 4;
      int r   = r0 + row;
      const float* src = (r < G_LEN) ? glob + (size_t)r * E_DIM
                                     : tok + (size_t)(r - G_LEN) * E_DIM;
      float4 v = *(const float4*)&src[c0 + c4];
      half4 h;
      h[0] = (_Float16)v.x; h[1] = (_Float16)v.y; h[2] = (_Float16)v.z; h[3] = (_Float16)v.w;
      *(half4*)&tile[row * 132 + c4] = h;
    }
    __syncthreads();
    _Float16* Xp = (_Float16*)(ws + OFF_XP);
#pragma unroll
    for (int uu = 0; uu < 4; ++uu) {
      int u    = tid + uu * 256;
      int kb_l = u >> 6;
      int row  = u & 63;
      half4 a = *(const half4*)&tile[row * 132 + kb_l * 8];
      half4 b = *(const half4*)&tile[row * 132 + kb_l * 8 + 4];
      half8 o;
      o[0] = a[0]; o[1] = a[1]; o[2] = a[2]; o[3] = a[3];
      o[4] = b[0]; o[5] = b[1]; o[6] = b[2]; o[7] = b[3];
      int kb = (c0 >> 3) + kb_l;
      *(half8*)&Xp[((size_t)kb * R_TOT + r0 + row) * 8] = o;
    }
  } else {
    int t = (bx - 1040) * 256 + tid;
    const int NW = 4 * KBLK * 1024;
    if (t < NW) {
      int w   = t >> 17;
      int rem = t & 131071;
      int kb  = rem >> 10;
      int n   = rem & 1023;
      const float* W = (w == 0) ? Wq : (w == 1) ? Wk : (w == 2) ? Wv : Wo;
      half8 v;
#pragma unroll
      for (int j = 0; j < 8; ++j)
        v[j] = (_Float16)W[(size_t)(kb * 8 + j) * 1024 + n];
      *(half8*)(ws + OFF_WP + (size_t)w * SZ_WP1 + (size_t)(kb * 1024 + n) * 16) = v;
    } else {
      int t2 = t - NW;
      if (t2 < R_TOT) {
        _Float16* fh = (_Float16*)(ws + OFF_FH);
        float m = (t2 < G_LEN) ? 0.0f : mask[t2 - G_LEN];
        fh[t2] = (_Float16)__expf(m);
      }
    }
  }
}

// ---------------- shared GEMM mainloop (R6 dual-LDS, swapped mfma) ----------------
__device__ __forceinline__ void gemm_tile(const _Float16* __restrict__ Ap,
                                          const _Float16* __restrict__ Bp,
                                          int m0, int n0, _Float16* lds,
                                          floatx4 acc[4][4]) {
  const int tid  = threadIdx.x;
  const int wave = tid >> 6;
  const int lane = tid & 63;
  const int quad = lane >> 4;
  const int l16  = lane & 15;
  _Float16* As = lds;
  _Float16* Bs = lds + 8 * 128 * 8;
  const int wm = (wave >> 1) * 64;
  const int wn = (wave & 1) * 64;
  for (int step = 0; step < 16; ++step) {
#pragma unroll
    for (int ui = 0; ui < 8; ++ui) {
      const int u   = wave * 8 + ui;   // 32 units: 16 A, 16 B
      const int isB = u >> 4;
      const int vv  = u & 15;
      const int kb  = vv >> 1;
      const int rh  = vv & 1;
      const _Float16* src =
          isB ? Bp + (size_t)((step * 8 + kb) * 1024 + n0 + rh * 64 + lane) * 8
              : Ap + (size_t)((step * 8 + kb) * R_TOT + m0 + rh * 64 + lane) * 8;
      _Float16* dst = (isB ? Bs : As) + (kb * 128 + rh * 64) * 8;
      gl_lds16(src, dst);
    }
    __syncthreads();
#pragma unroll
    for (int kk = 0; kk < 2; ++kk) {
      half8 af[4], bf[4];
#pragma unroll
      for (int mt = 0; mt < 4; ++mt)
        af[mt] = *(const half8*)(As + ((kk * 4 + quad) * 128 + wm + mt * 16 + l16) * 8);
#pragma unroll
      for (int nt = 0; nt < 4; ++nt)
        bf[nt] = *(const half8*)(Bs + ((kk * 4 + quad) * 128 + wn + nt * 16 + l16) * 8);
#pragma unroll
      for (int mt = 0; mt < 4; ++mt)
#pragma unroll
        for (int nt = 0; nt < 4; ++nt)
          acc[mt][nt] = __builtin_amdgcn_mfma_f32_16x16x32_f16(bf[nt], af[mt], acc[mt][nt], 0, 0, 0);
    }
    __syncthreads();
  }
}

// ---------------- stage 1: fused Q/K/V projections (single dispatch) ----------------
__global__ __launch_bounds__(256) void qkv_gemm_k(char* __restrict__ ws) {
  __shared__ __align__(16) _Float16 lds[2 * 8 * 128 * 8];   // 32 KB
  const int z  = blockIdx.x >> 3;                           // 0=Q 1=K 2=V
  const int n0 = (blockIdx.x & 7) * 128;
  const int m0 = blockIdx.y * 128;
  floatx4 acc[4][4];
#pragma unroll
  for (int a = 0; a < 4; ++a)
#pragma unroll
    for (int b = 0; b < 4; ++b) acc[a][b] = zero4();
  gemm_tile((const _Float16*)(ws + OFF_XP),
            (const _Float16*)(ws + OFF_WP + (size_t)z * SZ_WP1), m0, n0, lds, acc);

  const int lane = threadIdx.x & 63, wave = threadIdx.x >> 6;
  const int quad = lane >> 4, l16 = lane & 15;
  const int wm = (wave >> 1) * 64, wn = (wave & 1) * 64;
  if (z < 2) {
    _Float16* dst = (_Float16*)(ws + (z == 0 ? OFF_QP : OFF_KP));
    const float scale = (z == 0) ? QSCALE : 1.0f;
#pragma unroll
    for (int mt = 0; mt < 4; ++mt)
#pragma unroll
      for (int nt = 0; nt < 4; ++nt) {
        int m  = m0 + wm + mt * 16 + l16;
        int nb = n0 + wn + nt * 16 + quad * 4;
        half4 h;
#pragma unroll
        for (int r = 0; r < 4; ++r) h[r] = (_Float16)(acc[mt][nt][r] * scale);
        int db = (nb >> 6) * 8 + ((nb & 63) >> 3);
        *(half4*)&dst[((size_t)db * R_TOT + m) * 8 + (nb & 7)] = h;
      }
  } else {
    _Float16* dst = (_Float16*)(ws + OFF_VP);
    const _Float16* fh = (const _Float16*)(ws + OFF_FH);
#pragma unroll
    for (int mt = 0; mt < 4; ++mt) {
      int m = m0 + wm + mt * 16 + l16;
      float fhm = (float)fh[m];
#pragma unroll
      for (int nt = 0; nt < 4; ++nt) {
        int nl = n0 + wn + nt * 16 + quad * 4;
#pragma unroll
        for (int r = 0; r < 4; ++r) {
          int n = nl + r;
          dst[(((size_t)(n >> 6) * XBLK + (m >> 3)) * 64 + (n & 63)) * 8 + (m & 7)] =
              (_Float16)(acc[mt][nt][r] * fhm);
        }
      }
    }
  }
}

// ---------------- attention core: 64 queries/wave (two 32-q groups share K/V) ----------------
// Per chunk: one kf[4] load feeds both groups' QK MFMAs; V/f loads shared. Group B's
// QK MFMAs are independent of group A's exp chain -> intra-wave MFMA||VALU overlap.
__device__ __forceinline__ void attn_core64(const _Float16* __restrict__ Kph,
                                            const _Float16* __restrict__ Vph,
                                            const _Float16* __restrict__ fh,
                                            const half8 qaA[4], const half8 qaB[4],
                                            int lane, int off, int seam, int nch,
                                            floatx16& o0A, floatx16& o1A, floatx16& lA,
                                            floatx16& o0B, floatx16& o1B, floatx16& lB) {
  const int  half_ = lane >> 5;
  const int  c     = lane & 31;
  const bool hb    = half_ != 0;
  auto kbof = [&](int ci) { return ci * 32 + ((ci >= seam) ? off : 0); };

  half8 kf[4];
#pragma unroll
  for (int ks = 0; ks < 4; ++ks)
    kf[ks] = *(const half8*)&Kph[(size_t)((ks * 2 + half_) * R_TOT + kbof(0) + c) * 8];

  for (int ci = 0; ci < nch; ++ci) {
    const int kb = kbof(ci);
    // shared V + f loads (independent of s-chains)
    const int xb = kb >> 3;
    half8 vA0 = *(const half8*)&Vph[(size_t)((xb + half_) * 64 + c) * 8];
    half8 vA1 = *(const half8*)&Vph[(size_t)((xb + 2 + half_) * 64 + c) * 8];
    half8 vB0 = *(const half8*)&Vph[(size_t)((xb + half_) * 64 + 32 + c) * 8];
    half8 vB1 = *(const half8*)&Vph[(size_t)((xb + 2 + half_) * 64 + 32 + c) * 8];
    half8 f0 = *(const half8*)&fh[kb + half_ * 8];
    half8 f1 = *(const half8*)&fh[kb + 16 + half_ * 8];
    // QK for both groups off the same kf
    floatx16 sA = zero16(), sB = zero16();
#pragma unroll
    for (int ks = 0; ks < 4; ++ks) {
      sA = __builtin_amdgcn_mfma_f32_32x32x16_f16(kf[ks], qaA[ks], sA, 0, 0, 0);
      sB = __builtin_amdgcn_mfma_f32_32x32x16_f16(kf[ks], qaB[ks], sB, 0, 0, 0);
    }
    // kf dead -> prefetch next chunk's K while exp chains run
    const int kbn = kbof(ci + 1 < nch ? ci + 1 : ci);
#pragma unroll
    for (int ks = 0; ks < 4; ++ks)
      kf[ks] = *(const half8*)&Kph[(size_t)((ks * 2 + half_) * R_TOT + kbn + c) * 8];
    // ---- group A ----
    {
      int pk[8];
#pragma unroll
      for (int i = 0; i < 8; ++i)
        pk[i] = pk_f16x2(__builtin_amdgcn_exp2f(sA[2 * i]), __builtin_amdgcn_exp2f(sA[2 * i + 1]));
      int sw[8];
#pragma unroll
      for (int i = 0; i < 8; ++i) sw[i] = __shfl_xor(pk[i], 32);
      int4 bi0, bi1;
      bi0.x = hb ? sw[2] : pk[0];  bi0.y = hb ? sw[3] : pk[1];
      bi0.z = hb ? pk[2] : sw[0];  bi0.w = hb ? pk[3] : sw[1];
      bi1.x = hb ? sw[6] : pk[4];  bi1.y = hb ? sw[7] : pk[5];
      bi1.z = hb ? pk[6] : sw[4];  bi1.w = hb ? pk[7] : sw[5];
      half8 b0 = __builtin_bit_cast(half8, bi0);
      half8 b1 = __builtin_bit_cast(half8, bi1);
      lA  = __builtin_amdgcn_mfma_f32_32x32x16_f16(f0, b0, lA, 0, 0, 0);
      lA  = __builtin_amdgcn_mfma_f32_32x32x16_f16(f1, b1, lA, 0, 0, 0);
      o0A = __builtin_amdgcn_mfma_f32_32x32x16_f16(vA0, b0, o0A, 0, 0, 0);
      o0A = __builtin_amdgcn_mfma_f32_32x32x16_f16(vA1, b1, o0A, 0, 0, 0);
      o1A = __builtin_amdgcn_mfma_f32_32x32x16_f16(vB0, b0, o1A, 0, 0, 0);
      o1A = __builtin_amdgcn_mfma_f32_32x32x16_f16(vB1, b1, o1A, 0, 0, 0);
    }
    // ---- group B ----
    {
      int pk[8];
#pragma unroll
      for (int i = 0; i < 8; ++i)
        pk[i] = pk_f16x2(__builtin_amdgcn_exp2f(sB[2 * i]), __builtin_amdgcn_exp2f(sB[2 * i + 1]));
      int sw[8];
#pragma unroll
      for (int i = 0; i < 8; ++i) sw[i] = __shfl_xor(pk[i], 32);
      int4 bi0, bi1;
      bi0.x = hb ? sw[2] : pk[0];  bi0.y = hb ? sw[3] : pk[1];
      bi0.z = hb ? pk[2] : sw[0];  bi0.w = hb ? pk[3] : sw[1];
      bi1.x = hb ? sw[6] : pk[4];  bi1.y = hb ? sw[7] : pk[5];
      bi1.z = hb ? pk[6] : sw[4];  bi1.w = hb ? pk[7] : sw[5];
      half8 b0 = __builtin_bit_cast(half8, bi0);
      half8 b1 = __builtin_bit_cast(half8, bi1);
      lB  = __builtin_amdgcn_mfma_f32_32x32x16_f16(f0, b0, lB, 0, 0, 0);
      lB  = __builtin_amdgcn_mfma_f32_32x32x16_f16(f1, b1, lB, 0, 0, 0);
      o0B = __builtin_amdgcn_mfma_f32_32x32x16_f16(vA0, b0, o0B, 0, 0, 0);
      o0B = __builtin_amdgcn_mfma_f32_32x32x16_f16(vA1, b1, o0B, 0, 0, 0);
      o1B = __builtin_amdgcn_mfma_f32_32x32x16_f16(vB0, b0, o1B, 0, 0, 0);
      o1B = __builtin_amdgcn_mfma_f32_32x32x16_f16(vB1, b1, o1B, 0, 0, 0);
    }
  }
}

// ---------------- stage 2: fused attention (glob blocks first, local backfills) ----------------
// glob: 80 blocks — block = (h, split-pair); waves 0,1 -> split 2*sp2 (q 0-63 / 64-127),
//       waves 2,3 -> split 2*sp2+1. local: 512 blocks — block = (h, blk, half), wave w
//       covers 64 queries.
__global__ __launch_bounds__(256) void attn_k(char* __restrict__ ws) {
  const int wave = threadIdx.x >> 6, lane = threadIdx.x & 63;
  const int bx = blockIdx.x;
  const _Float16* fh = (const _Float16*)(ws + OFF_FH);
  const int half_ = lane >> 5, c = lane & 31;
  if (bx < 80) {
    const int h = bx / 5, sp2 = bx % 5;
    const int spl = sp2 * 2 + (wave >> 1);
    const int qbase = (wave & 1) * 64;
    const _Float16* Qph = (const _Float16*)(ws + OFF_QP) + (size_t)h * 8 * R_TOT * 8;
    const _Float16* Kph = (const _Float16*)(ws + OFF_KP) + (size_t)h * 8 * R_TOT * 8;
    const _Float16* Vph = (const _Float16*)(ws + OFF_VP) + (size_t)h * XBLK * 64 * 8;
    half8 qaA[4], qaB[4];
#pragma unroll
    for (int ks = 0; ks < 4; ++ks) {
      qaA[ks] = *(const half8*)&Qph[(size_t)((ks * 2 + half_) * R_TOT + qbase + c) * 8];
      qaB[ks] = *(const half8*)&Qph[(size_t)((ks * 2 + half_) * R_TOT + qbase + 32 + c) * 8];
    }
    floatx16 o0A = zero16(), o1A = zero16(), lA = zero16();
    floatx16 o0B = zero16(), o1B = zero16(), lB = zero16();
    attn_core64(Kph, Vph, fh, qaA, qaB, lane, spl * SPLW, 0, SPLW / 32,
                o0A, o1A, lA, o0B, o1B, lB);
    float* Og = (float*)(ws + OFF_OG);
    float* Lg = (float*)(ws + OFF_LG);
#pragma unroll
    for (int g2 = 0; g2 < 2; ++g2) {
      const floatx16& o0 = g2 ? o0B : o0A;
      const floatx16& o1 = g2 ? o1B : o1A;
      const floatx16& l  = g2 ? lB  : lA;
      const int q = qbase + g2 * 32 + c;
#pragma unroll
      for (int g = 0; g < 4; ++g) {
        float4 fa, fb;
        fa.x = o0[4 * g]; fa.y = o0[4 * g + 1]; fa.z = o0[4 * g + 2]; fa.w = o0[4 * g + 3];
        fb.x = o1[4 * g]; fb.y = o1[4 * g + 1]; fb.z = o1[4 * g + 2]; fb.w = o1[4 * g + 3];
        *(float4*)&Og[((size_t)(spl * H_NUM + h) * 128 + q) * 64 + 8 * g + 4 * half_] = fa;
        *(float4*)&Og[((size_t)(spl * H_NUM + h) * 128 + q) * 64 + 32 + 8 * g + 4 * half_] = fb;
      }
      if (half_ == 0) Lg[(spl * H_NUM + h) * 128 + q] = l[0];
    }
  } else {
    const int item = bx - 80;
    const int h = item >> 5, rem = item & 31;
    const int blk = rem >> 1, qh = rem & 1;
    const int qbase = G_LEN + blk * BS_LEN + qh * 256 + wave * 64;
    const _Float16* Qph = (const _Float16*)(ws + OFF_QP) + (size_t)h * 8 * R_TOT * 8;
    const _Float16* Kph = (const _Float16*)(ws + OFF_KP) + (size_t)h * 8 * R_TOT * 8;
    const _Float16* Vph = (const _Float16*)(ws + OFF_VP) + (size_t)h * XBLK * 64 * 8;
    half8 qaA[4], qaB[4];
#pragma unroll
    for (int ks = 0; ks < 4; ++ks) {
      qaA[ks] = *(const half8*)&Qph[(size_t)((ks * 2 + half_) * R_TOT + qbase + c) * 8];
      qaB[ks] = *(const half8*)&Qph[(size_t)((ks * 2 + half_) * R_TOT + qbase + 32 + c) * 8];
    }
    floatx16 o0A = zero16(), o1A = zero16(), lA = zero16();
    floatx16 o0B = zero16(), o1B = zero16(), lB = zero16();
    attn_core64(Kph, Vph, fh, qaA, qaB, lane, blk * BS_LEN, 4, 20,
                o0A, o1A, lA, o0B, o1B, lB);
    _Float16* AOp = (_Float16*)(ws + OFF_AOP);
#pragma unroll
    for (int g2 = 0; g2 < 2; ++g2) {
      const floatx16& o0 = g2 ? o0B : o0A;
      const floatx16& o1 = g2 ? o1B : o1A;
      const floatx16& l  = g2 ? lB  : lA;
      const float inv = 1.0f / l[0];
      const int m = qbase + g2 * 32 + c;
#pragma unroll
      for (int g = 0; g < 4; ++g) {
        half4 ha, hc;
#pragma unroll
        for (int i = 0; i < 4; ++i) {
          ha[i] = (_Float16)(o0[4 * g + i] * inv);
          hc[i] = (_Float16)(o1[4 * g + i] * inv);
        }
        *(half4*)&AOp[((size_t)(h * 8 + g) * R_TOT + m) * 8 + 4 * half_] = ha;
        *(half4*)&AOp[((size_t)(h * 8 + 4 + g) * R_TOT + m) * 8 + 4 * half_] = hc;
      }
    }
  }
}

// ---------------- stage 2c: combine global partials ----------------
__global__ void combine_k(char* __restrict__ ws) {
  int idx = blockIdx.x * 256 + threadIdx.x;   // H*128*64 = 131072
  int h = idx >> 13, rem = idx & 8191, q = rem >> 6, d = rem & 63;
  const float* Og = (const float*)(ws + OFF_OG);
  const float* Lg = (const float*)(ws + OFF_LG);
  float o = 0.0f, l = 0.0f;
#pragma unroll
  for (int s = 0; s < NSPL; ++s) {
    o += Og[(size_t)((s * H_NUM + h) * 128 + q) * 64 + d];
    l += Lg[(s * H_NUM + h) * 128 + q];
  }
  int n = h * 64 + d;
  ((_Float16*)(ws + OFF_AOP))[((size_t)(n >> 3) * R_TOT + q) * 8 + (n & 7)] = (_Float16)(o / l);
}

// ---------------- stage 3: output projection -> d_out (fp32, float4 stores) ----------------
__global__ __launch_bounds__(256) void out_gemm_k(char* __restrict__ ws, float* __restrict__ dout) {
  __shared__ __align__(16) _Float16 lds[2 * 8 * 128 * 8];
  const int m0 = blockIdx.y * 128;
  const int n0 = blockIdx.x * 128;
  floatx4 acc[4][4];
#pragma unroll
  for (int a = 0; a < 4; ++a)
#pragma unroll
    for (int b = 0; b < 4; ++b) acc[a][b] = zero4();
  gemm_tile((const _Float16*)(ws + OFF_AOP),
            (const _Float16*)(ws + OFF_WP + 3 * (size_t)SZ_WP1), m0, n0, lds, acc);
  const int lane = threadIdx.x & 63, wave = threadIdx.x >> 6;
  const int quad = lane >> 4, l16 = lane & 15;
  const int wm = (wave >> 1) * 64, wn = (wave & 1) * 64;
#pragma unroll
  for (int mt = 0; mt < 4; ++mt)
#pragma unroll
    for (int nt = 0; nt < 4; ++nt) {
      int m  = m0 + wm + mt * 16 + l16;
      int nb = n0 + wn + nt * 16 + quad * 4;
      float4 f4;
      f4.x = acc[mt][nt][0]; f4.y = acc[mt][nt][1];
      f4.z = acc[mt][nt][2]; f4.w = acc[mt][nt][3];
      float* p = (m < G_LEN) ? (dout + (size_t)S_LEN * E_DIM + (size_t)m * E_DIM + nb)
                             : (dout + (size_t)(m - G_LEN) * E_DIM + nb);
      *(float4*)p = f4;
    }
}

extern "C" void kernel_launch(void* const* d_in, const int* in_sizes, int n_in,
                              void* d_out, int out_size, void* d_ws, size_t ws_size,
                              hipStream_t stream) {
  const float* tok  = (const float*)d_in[0];
  const float* glob = (const float*)d_in[1];
  const float* mask = (const float*)d_in[2];
  const float* Wq   = (const float*)d_in[3];
  const float* Wk   = (const float*)d_in[4];
  const float* Wv   = (const float*)d_in[5];
  const float* Wo   = (const float*)d_in[6];
  char*  ws   = (char*)d_ws;
  float* dout = (float*)d_out;

  prep_k<<<dim3(1040 + 2081), dim3(256), 0, stream>>>(tok, glob, Wq, Wk, Wv, Wo, mask, ws);
  qkv_gemm_k<<<dim3(24, 65), dim3(256), 0, stream>>>(ws);
  attn_k<<<dim3(80 + 512), dim3(256), 0, stream>>>(ws);
  combine_k<<<dim3(512), dim3(256), 0, stream>>>(ws);
  out_gemm_k<<<dim3(8, 65), dim3(256), 0, stream>>>(ws, dout);
}